// Round 17
// baseline (210.130 us; speedup 1.0000x reference)
//
#include <hip/hip_runtime.h>
#include <stdint.h>
#include <stddef.h>

// FastChannelAttention on MI355X — Gram-refactored pipeline.
//   S[b,h] = Wq_h^T (X_b^T X_b) Wk_h ;  out = X_b (Wv M_b) + bias
//   R16: k_xcp transposer -> 512 thr/block, 4tok x 8ch per thread (same
//   128x128 tile, 32KB LDS) to double resident waves; latency-bound fix.

typedef unsigned short u16;
typedef __attribute__((ext_vector_type(4))) unsigned short u16x4;
typedef __attribute__((ext_vector_type(8))) unsigned short u16x8;
typedef __attribute__((ext_vector_type(8))) __bf16 bf16x8;
typedef __attribute__((ext_vector_type(4))) float f32x4;

#define B_DIM 4
#define N_TOK 16384
#define C_DIM 512
#define CQ3   1536
#define NROWS 65536

__constant__ int PTI[10] = {0, 0, 0, 0, 1, 1, 1, 2, 2, 3};
__constant__ int PTJ[10] = {0, 1, 2, 3, 1, 2, 3, 2, 3, 3};

__device__ __forceinline__ u16 f2bf(float f) {              // RNE fp32->bf16
  union { float f; uint32_t u; } v; v.f = f;
  uint32_t r = v.u + 0x7FFFu + ((v.u >> 16) & 1u);
  return (u16)(r >> 16);
}
__device__ __forceinline__ float bf2f(u16 u) {
  union { uint32_t u; float f; } v; v.u = ((uint32_t)u) << 16;
  return v.f;
}
__device__ __forceinline__ bf16x8 as_bf16x8(u16x8 u) {
  union { u16x8 u; bf16x8 b; } v; v.u = u; return v.b;
}
__device__ __forceinline__ bf16x8 ldfrag(const u16* p) {
  return as_bf16x8(*(const u16x8*)p);
}
__device__ __forceinline__ void gl_lds16(const void* g, void* l) {
  __builtin_amdgcn_global_load_lds(
      (const __attribute__((address_space(1))) uint32_t*)g,
      (__attribute__((address_space(3))) uint32_t*)l, 16, 0, 0);
}
#define VMDRAIN asm volatile("s_waitcnt vmcnt(0)" ::: "memory")
#define VM4     asm volatile("s_waitcnt vmcnt(4)" ::: "memory")
#define VM8     asm volatile("s_waitcnt vmcnt(8)" ::: "memory")

// ---------------- k_xcp: fused x->xb+xbT transpose AND weight prep (512 thr) ----------------
__global__ __launch_bounds__(512) void k_xcp(const float* __restrict__ x,
                                             u16* __restrict__ xb,
                                             u16* __restrict__ xbT,
                                             const float* __restrict__ qkv_w,
                                             const float* __restrict__ proj_w,
                                             u16* __restrict__ wl,
                                             u16* __restrict__ pwl,
                                             u16* __restrict__ vA) {
  __shared__ __align__(16) u16 T[16384];        // [c_loc 128][pc 16][8] u16
  const int bi = blockIdx.x;                    // 2368 = 2048 xc + 320 prep
  const int tid = threadIdx.x;
  if (bi >= 2048) {
    int g = (bi - 2048) * 512 + tid;            // 0..163839
    if (g < 98304) {                            // wl slots
      int c8 = g / CQ3, j = g - c8 * CQ3;
      u16x8 o;
#pragma unroll
      for (int i = 0; i < 8; ++i) o[i] = f2bf(qkv_w[(size_t)(c8 * 8 + i) * CQ3 + j]);
      *(u16x8*)(wl + (size_t)g * 8) = o;
    } else if (g < 131072) {                    // pwl slots
      int gg = g - 98304;
      int d8 = gg >> 9, j = gg & 511;
      u16x8 o;
#pragma unroll
      for (int i = 0; i < 8; ++i) o[i] = f2bf(proj_w[(size_t)(d8 * 8 + i) * 512 + j]);
      *(u16x8*)(pwl + (size_t)gg * 8) = o;
    } else {                                    // vA row-major chunks
      int gg = g - 131072;
      int c = gg >> 6, q = gg & 63;
      const float* s = qkv_w + (size_t)c * CQ3 + 1024 + q * 8;
      float4 v0 = *(const float4*)s, v1 = *(const float4*)(s + 4);
      u16x8 o;
      o[0] = f2bf(v0.x); o[1] = f2bf(v0.y); o[2] = f2bf(v0.z); o[3] = f2bf(v0.w);
      o[4] = f2bf(v1.x); o[5] = f2bf(v1.y); o[6] = f2bf(v1.z); o[7] = f2bf(v1.w);
      *(u16x8*)(vA + (size_t)gg * 8) = o;
    }
    return;
  }
  const int b = bi >> 9, tt = (bi >> 2) & 127, ct = bi & 3;
  const int n0 = tt * 128, c0 = ct * 128;
  const int cb8 = (tid & 15) * 8;               // channel sub-block (8 ch)
  const int tch = tid >> 4;                     // token 4-chunk 0..31
  const float* src = x + (size_t)(b * N_TOK + n0 + tch * 4) * C_DIM + c0 + cb8;
  float v[4][8];
#pragma unroll
  for (int j = 0; j < 4; ++j) {
    float4 a0 = *(const float4*)(src + (size_t)j * C_DIM);
    float4 a1 = *(const float4*)(src + (size_t)j * C_DIM + 4);
    v[j][0] = a0.x; v[j][1] = a0.y; v[j][2] = a0.z; v[j][3] = a0.w;
    v[j][4] = a1.x; v[j][5] = a1.y; v[j][6] = a1.z; v[j][7] = a1.w;
  }
  u16* xbd = xb + (size_t)(b * N_TOK + n0 + tch * 4) * C_DIM + c0 + cb8;
#pragma unroll
  for (int j = 0; j < 4; ++j) {
    u16x8 o;
#pragma unroll
    for (int i = 0; i < 8; ++i) o[i] = f2bf(v[j][i]);
    *(u16x8*)(xbd + (size_t)j * C_DIM) = o;
  }
  // LDS transposed: thread writes 4 tokens (8B) per channel; pc = chunk ^ ((c_loc>>3)&15)
  {
    const int pc = (tch >> 1) ^ (tid & 15);     // (c_loc>>3)&15 == tid&15 for all i
    const int half = tch & 1;
#pragma unroll
    for (int i = 0; i < 8; ++i) {
      int c_loc = cb8 + i;
      u16x4 o;
#pragma unroll
      for (int j = 0; j < 4; ++j) o[j] = f2bf(v[j][i]);
      *(u16x4*)&T[c_loc * 128 + pc * 8 + half * 4] = o;
    }
  }
  __syncthreads();
#pragma unroll
  for (int q = 0; q < 4; ++q) {
    int idx = q * 512 + tid;                    // 0..2047
    int c_loc = idx >> 4, ch = idx & 15;        // 128 rows x 16 chunks
    int pc = ch ^ ((c_loc >> 3) & 15);
    u16x8 o = *(const u16x8*)&T[c_loc * 128 + pc * 8];
    *(u16x8*)&xbT[(size_t)(b * C_DIM + c0 + c_loc) * N_TOK + n0 + ch * 8] = o;
  }
}

// ---------------- k_g: Gram partials, triangle pairs, counted vmcnt(8) ----------------
__global__ __launch_bounds__(256) void k_g(const u16* __restrict__ xbT, u16* __restrict__ Gp) {
  __shared__ __align__(16) u16 As[2][8192];   // [buf][idx 128][kblk 8][8], pre-swizzled k
  __shared__ __align__(16) u16 Bs[2][8192];
  const int tid = threadIdx.x, lane = tid & 63, wid = tid >> 6;
  const int orig = blockIdx.x;                  // 640 = 8 x 80 bijective swizzle
  const int wg = (orig & 7) * 80 + (orig >> 3);
  const int kc = wg / 40, rem = wg % 40;
  const int b = rem / 10, p = rem % 10;
  const int ti = PTI[p], tj = PTJ[p];
  const u16* abase = xbT + ((size_t)b * 512 + ti * 128) * N_TOK + kc * 1024;
  const u16* bbase = xbT + ((size_t)b * 512 + tj * 128) * N_TOK + kc * 1024;
  const int wr = wid >> 1, wc = wid & 1;

  auto stage = [&](int kb, int buf) {           // 8 loads/thread
#pragma unroll
    for (int s4 = 0; s4 < 4; ++s4) {
      int slot = s4 * 256 + tid;
      int idx = slot >> 3, kblk = slot & 7;
      int kcol = kb * 64 + ((kblk ^ (idx & 7)) * 8);
      gl_lds16(abase + (size_t)idx * N_TOK + kcol, &As[buf][slot * 8]);
      gl_lds16(bbase + (size_t)idx * N_TOK + kcol, &Bs[buf][slot * 8]);
    }
  };

  f32x4 acc[4][4];
#pragma unroll
  for (int i = 0; i < 4; ++i)
#pragma unroll
    for (int j = 0; j < 4; ++j) acc[i][j] = (f32x4){0.f, 0.f, 0.f, 0.f};

  stage(0, 0);
  for (int kb = 0; kb < 16; ++kb) {
    const int cur = kb & 1;
    if (kb < 15) {
      stage(kb + 1, cur ^ 1);                   // next tile flies through MFMA
      VM8;                                      // current tile landed (newest 8 allowed)
    } else {
      VMDRAIN;
    }
    __builtin_amdgcn_s_barrier();               // current tile collectively visible
#pragma unroll
    for (int kk = 0; kk < 2; ++kk) {
      const int krow = kk * 4 + (lane >> 4);
      const int pk = krow ^ (lane & 7);
      bf16x8 af[4], bfr[4];
#pragma unroll
      for (int t = 0; t < 4; ++t)
        af[t] = *(const bf16x8*)&As[cur][((wr * 64 + t * 16 + (lane & 15)) * 8 + pk) * 8];
#pragma unroll
      for (int t = 0; t < 4; ++t)
        bfr[t] = *(const bf16x8*)&Bs[cur][((wc * 64 + t * 16 + (lane & 15)) * 8 + pk) * 8];
      __builtin_amdgcn_s_setprio(1);
#pragma unroll
      for (int mt = 0; mt < 4; ++mt)
#pragma unroll
        for (int nt = 0; nt < 4; ++nt)
          acc[mt][nt] = __builtin_amdgcn_mfma_f32_16x16x32_bf16(af[mt], bfr[nt], acc[mt][nt], 0, 0, 0);
      __builtin_amdgcn_s_setprio(0);
    }
    __builtin_amdgcn_s_barrier();               // readers done before next overwrite
  }
  // epilogue: 64x64 bf16 per wave via wave-private 8KB slice of As
  u16* wsl = &As[0][0] + wid * 4096;
#pragma unroll
  for (int mt = 0; mt < 4; ++mt)
#pragma unroll
    for (int nt = 0; nt < 4; ++nt)
#pragma unroll
      for (int r = 0; r < 4; ++r) {
        int row = mt * 16 + (lane >> 4) * 4 + r;
        int col = nt * 16 + (lane & 15);
        int slot = (col >> 3) ^ (row & 7);
        wsl[row * 64 + slot * 8 + (col & 7)] = f2bf(acc[mt][nt][r]);
      }
  u16* gdst = Gp + (size_t)(kc * 4 + b) * 262144;
#pragma unroll
  for (int it = 0; it < 8; ++it) {
    int rr = it * 8 + (lane >> 3);
    int slot = (lane & 7) ^ (rr & 7);
    *(u16x8*)&gdst[(size_t)(ti * 128 + wr * 64 + rr) * 512 + tj * 128 + wc * 64 + (lane & 7) * 8] =
        *(const u16x8*)&wsl[rr * 64 + slot * 8];
  }
}

// ---------------- k_red: G(upper) = sum_kc Gp; mirror folded in ----------------
__global__ __launch_bounds__(256) void k_red(const u16* __restrict__ Gp, u16* __restrict__ G) {
  const int bi = blockIdx.x;                    // 320 = b(4) x p(10) x slice(8)
  const int b = bi / 80, rem = bi % 80;
  const int p = rem >> 3, sl = rem & 7;
  const int ti = PTI[p], tj = PTJ[p];
  const int tid = threadIdx.x;
  const int row = sl * 16 + (tid >> 4);         // 0..127 within tile
  const int c0 = (tid & 15) * 8;                // col chunk
  const size_t off = (size_t)(ti * 128 + row) * 512 + tj * 128 + c0;
  float s[8];
#pragma unroll
  for (int i = 0; i < 8; ++i) s[i] = 0.f;
  const u16* src = Gp + (size_t)b * 262144 + off;
#pragma unroll 4
  for (int kc = 0; kc < 16; ++kc) {
    u16x8 v = *(const u16x8*)(src + (size_t)kc * 1048576);
#pragma unroll
    for (int i = 0; i < 8; ++i) s[i] += bf2f(v[i]);
  }
  u16x8 o;
#pragma unroll
  for (int i = 0; i < 8; ++i) o[i] = f2bf(s[i]);
  u16* gb = G + (size_t)b * 262144;
  *(u16x8*)(gb + off) = o;
  if (ti != tj) {                               // mirror: G[c][r] = G[r][c]
#pragma unroll
    for (int i = 0; i < 8; ++i)
      gb[(size_t)(tj * 128 + c0 + i) * 512 + ti * 128 + row] = o[i];
  }
}

// ---------------- k_gq: Gqk = G @ [Wq|Wk]  (blocks >=128: xb L3 prewarm) ----------------
__global__ __launch_bounds__(256) void k_gq(const u16* __restrict__ G,
                                            const u16* __restrict__ wl,
                                            u16* __restrict__ Gqk,
                                            const u16* __restrict__ xb) {
  const int bi = blockIdx.x;                     // 1152 = 128 compute + 1024 prewarm
  if (bi >= 128) {
    const float4* p = (const float4*)xb;         // 67108864 B = 4194304 float4
    float sx = 0.f, sy = 0.f, sz = 0.f, sw = 0.f;
    for (size_t i = (size_t)(bi - 128) * 256 + threadIdx.x; i < 4194304;
         i += (size_t)1024 * 256) {
      float4 v = p[i];
      sx += v.x; sy += v.y; sz += v.z; sw += v.w;
    }
    asm volatile("" :: "v"(sx), "v"(sy), "v"(sz), "v"(sw));
    return;
  }
  const int b = bi >> 5, mt = (bi >> 3) & 3, nt2 = bi & 7;
  const int m0 = mt * 128, n0 = nt2 * 128;
  const int lane = threadIdx.x & 63, w = threadIdx.x >> 6;
  f32x4 acc[8][2];
#pragma unroll
  for (int i = 0; i < 8; ++i) { acc[i][0] = (f32x4){0,0,0,0}; acc[i][1] = (f32x4){0,0,0,0}; }
  for (int ks = 0; ks < 16; ++ks) {
    bf16x8 bfr[2];
#pragma unroll
    for (int nf = 0; nf < 2; ++nf)
      bfr[nf] = ldfrag(wl + ((size_t)(ks * 4 + (lane >> 4)) * CQ3 + n0 + w * 32 + nf * 16 + (lane & 15)) * 8);
#pragma unroll
    for (int mf = 0; mf < 8; ++mf) {
      bf16x8 af = ldfrag(G + (size_t)b * 262144 + (size_t)(m0 + mf * 16 + (lane & 15)) * 512 + ks * 32 + (lane >> 4) * 8);
#pragma unroll
      for (int nf = 0; nf < 2; ++nf)
        acc[mf][nf] = __builtin_amdgcn_mfma_f32_16x16x32_bf16(af, bfr[nf], acc[mf][nf], 0, 0, 0);
    }
  }
#pragma unroll
  for (int mf = 0; mf < 8; ++mf)
#pragma unroll
    for (int nf = 0; nf < 2; ++nf)
#pragma unroll
      for (int r = 0; r < 4; ++r) {
        int d = m0 + mf * 16 + (lane >> 4) * 4 + r;
        int j = n0 + w * 32 + nf * 16 + (lane & 15);
        Gqk[(size_t)b * 524288 + ((size_t)(d >> 3) * 1024 + j) * 8 + (d & 7)] = f2bf(acc[mf][nf][r]);
      }
}

// ---------------- k_s2: per (b,h) S, ssq, softmax, M ----------------
__global__ __launch_bounds__(256) void k_s2(const u16* __restrict__ Gqk,
                                            const u16* __restrict__ wl,
                                            const u16* __restrict__ pwl,
                                            const float* __restrict__ temp,
                                            u16* __restrict__ Ml) {
  __shared__ float Ssh[4][4096];
  __shared__ u16 At[64 * 72];
  __shared__ float ssqsh[128];
  __shared__ float rqk[128];
  const int tid = threadIdx.x, lane = tid & 63, w = tid >> 6;
  const int bh = blockIdx.x, b = bh >> 3, hh = bh & 7;
  if (tid < 128) ssqsh[tid] = 0.f;

  f32x4 acc[4][4];
#pragma unroll
  for (int i = 0; i < 4; ++i)
#pragma unroll
    for (int j = 0; j < 4; ++j) acc[i][j] = (f32x4){0.f, 0.f, 0.f, 0.f};
  for (int ks = 0; ks < 4; ++ks) {
    const int crow = w * 16 + ks * 4 + (lane >> 4);
    bf16x8 aq[4], bk[4];
#pragma unroll
    for (int mf = 0; mf < 4; ++mf)
      aq[mf] = ldfrag(wl + ((size_t)crow * CQ3 + hh * 64 + mf * 16 + (lane & 15)) * 8);
#pragma unroll
    for (int nf = 0; nf < 4; ++nf)
      bk[nf] = ldfrag(Gqk + (size_t)b * 524288 + ((size_t)crow * 1024 + 512 + hh * 64 + nf * 16 + (lane & 15)) * 8);
#pragma unroll
    for (int mf = 0; mf < 4; ++mf)
#pragma unroll
      for (int nf = 0; nf < 4; ++nf)
        acc[mf][nf] = __builtin_amdgcn_mfma_f32_16x16x32_bf16(aq[mf], bk[nf], acc[mf][nf], 0, 0, 0);
  }
#pragma unroll
  for (int mf = 0; mf < 4; ++mf)
#pragma unroll
    for (int nf = 0; nf < 4; ++nf)
#pragma unroll
      for (int r = 0; r < 4; ++r)
        Ssh[w][(mf * 16 + (lane >> 4) * 4 + r) * 64 + nf * 16 + (lane & 15)] = acc[mf][nf][r];
  __syncthreads();
  for (int idx = tid; idx < 4096; idx += 256)
    Ssh[0][idx] = Ssh[0][idx] + Ssh[1][idx] + Ssh[2][idx] + Ssh[3][idx];

  {
    const int d = tid & 63, part = tid >> 6;
    float sq = 0.f, sk = 0.f;
    for (int co = 0; co < 16; ++co) {
      int c8 = part * 16 + co;
      u16x8 wq = *(const u16x8*)(wl + ((size_t)c8 * CQ3 + hh * 64 + d) * 8);
      u16x8 gq = *(const u16x8*)(Gqk + (size_t)b * 524288 + ((size_t)c8 * 1024 + hh * 64 + d) * 8);
      u16x8 wk = *(const u16x8*)(wl + ((size_t)c8 * CQ3 + 512 + hh * 64 + d) * 8);
      u16x8 gk = *(const u16x8*)(Gqk + (size_t)b * 524288 + ((size_t)c8 * 1024 + 512 + hh * 64 + d) * 8);
#pragma unroll
      for (int i = 0; i < 8; ++i) {
        sq += bf2f(wq[i]) * bf2f(gq[i]);
        sk += bf2f(wk[i]) * bf2f(gk[i]);
      }
    }
    atomicAdd(&ssqsh[d], sq);
    atomicAdd(&ssqsh[64 + d], sk);
  }
  __syncthreads();
  if (tid < 128) rqk[tid] = 1.f / fmaxf(sqrtf(fmaxf(ssqsh[tid], 0.f)), 1e-12f);
  __syncthreads();

  {
    const float tp = temp[hh];
    const int d = tid >> 2, q4 = tid & 3;
    float vals[16];
    float mx = -3.0e38f;
    const float rqd = rqk[d];
#pragma unroll
    for (int i = 0; i < 16; ++i) {
      float v = Ssh[0][d * 64 + q4 * 16 + i] * rqd * rqk[64 + q4 * 16 + i] * tp;
      vals[i] = v; mx = fmaxf(mx, v);
    }
    mx = fmaxf(mx, __shfl_xor(mx, 1));
    mx = fmaxf(mx, __shfl_xor(mx, 2));
    float sum = 0.f;
#pragma unroll
    for (int i = 0; i < 16; ++i) { vals[i] = __expf(vals[i] - mx); sum += vals[i]; }
    sum += __shfl_xor(sum, 1);
    sum += __shfl_xor(sum, 2);
    const float inv = 1.f / sum;
#pragma unroll
    for (int i = 0; i < 16; ++i) At[(q4 * 16 + i) * 72 + d] = f2bf(vals[i] * inv);
  }
  __syncthreads();

  f32x4 acc2[4][8];
#pragma unroll
  for (int i = 0; i < 4; ++i)
#pragma unroll
    for (int j = 0; j < 8; ++j) acc2[i][j] = (f32x4){0.f, 0.f, 0.f, 0.f};
#pragma unroll
  for (int s = 0; s < 2; ++s) {
    bf16x8 af[4], bfr[8];
#pragma unroll
    for (int mf = 0; mf < 4; ++mf)
      af[mf] = *(const bf16x8*)&At[(mf * 16 + (lane & 15)) * 72 + s * 32 + (lane >> 4) * 8];
#pragma unroll
    for (int nf = 0; nf < 8; ++nf)
      bfr[nf] = ldfrag(pwl + ((size_t)(hh * 8 + s * 4 + (lane >> 4)) * 512 + w * 128 + nf * 16 + (lane & 15)) * 8);
#pragma unroll
    for (int mf = 0; mf < 4; ++mf)
#pragma unroll
      for (int nf = 0; nf < 8; ++nf)
        acc2[mf][nf] = __builtin_amdgcn_mfma_f32_16x16x32_bf16(af[mf], bfr[nf], acc2[mf][nf], 0, 0, 0);
  }
#pragma unroll
  for (int mf = 0; mf < 4; ++mf)
#pragma unroll
    for (int nf = 0; nf < 8; ++nf)
#pragma unroll
      for (int r = 0; r < 4; ++r) {
        int e = mf * 16 + (lane >> 4) * 4 + r;
        int j = w * 128 + nf * 16 + (lane & 15);
        int cc = hh * 64 + e;
        Ml[(size_t)b * 262144 + ((size_t)(cc >> 3) * 512 + j) * 8 + (cc & 7)] = f2bf(acc2[mf][nf][r]);
      }
}

// ---------------- k_p: Pl = Wv @ Ml ----------------
__global__ __launch_bounds__(256) void k_p(const u16* __restrict__ vA,
                                           const u16* __restrict__ Ml,
                                           u16* __restrict__ Pl) {
  const int bi = blockIdx.x;                     // 64: b(4) x ct(4) x jt(4)
  const int b = bi >> 4, ct = (bi >> 2) & 3, jt = bi & 3;
  const int m0 = ct * 128, j0 = jt * 128;
  const int lane = threadIdx.x & 63, w = threadIdx.x >> 6;
  f32x4 acc[8][2];
#pragma unroll
  for (int i = 0; i < 8; ++i) { acc[i][0] = (f32x4){0,0,0,0}; acc[i][1] = (f32x4){0,0,0,0}; }
  for (int ks = 0; ks < 16; ++ks) {
    bf16x8 bfr[2];
#pragma unroll
    for (int nf = 0; nf < 2; ++nf)
      bfr[nf] = ldfrag(Ml + (size_t)b * 262144 + ((size_t)(ks * 4 + (lane >> 4)) * 512 + j0 + w * 32 + nf * 16 + (lane & 15)) * 8);
#pragma unroll
    for (int mf = 0; mf < 8; ++mf) {
      bf16x8 af = ldfrag(vA + (size_t)(m0 + mf * 16 + (lane & 15)) * 512 + ks * 32 + (lane >> 4) * 8);
#pragma unroll
      for (int nf = 0; nf < 2; ++nf)
        acc[mf][nf] = __builtin_amdgcn_mfma_f32_16x16x32_bf16(af, bfr[nf], acc[mf][nf], 0, 0, 0);
    }
  }
#pragma unroll
  for (int mf = 0; mf < 8; ++mf)
#pragma unroll
    for (int nf = 0; nf < 2; ++nf)
#pragma unroll
      for (int r = 0; r < 4; ++r) {
        int c = m0 + mf * 16 + (lane >> 4) * 4 + r;
        int j = j0 + w * 32 + nf * 16 + (lane & 15);
        Pl[(size_t)b * 262144 + ((size_t)(c >> 3) * 512 + j) * 8 + (c & 7)] = f2bf(acc[mf][nf][r]);
      }
}

// ---------------- k_out: out = xb @ Pl + bias; BK=32 dbuf, counted vmcnt(4) ----------------
__global__ __launch_bounds__(256, 4) void k_out(const u16* __restrict__ xb,
                                                const u16* __restrict__ Pl,
                                                const float* __restrict__ pb,
                                                float* __restrict__ out) {
  __shared__ __align__(16) u16 L[16384];
  const int tid = threadIdx.x;
  const int orig = blockIdx.x;                   // 2048 = 8 x 256 bijective swizzle
  const int wg = (orig & 7) * 256 + (orig >> 3);
  const int cb = wg & 3, rb = wg >> 2;
  const int row0 = rb * 128, col0 = cb * 128;
  const int b = rb >> 7;
  const int lane = tid & 63, wid = tid >> 6;
  const int wr = wid >> 1, wc = wid & 1;
  float bias[4];
#pragma unroll
  for (int nt = 0; nt < 4; ++nt) bias[nt] = pb[col0 + wc * 64 + nt * 16 + (lane & 15)];

  f32x4 acc[4][4];
#pragma unroll
  for (int i = 0; i < 4; ++i)
#pragma unroll
    for (int j = 0; j < 4; ++j) acc[i][j] = (f32x4){0.f, 0.f, 0.f, 0.f};

  const u16* pbase = Pl + (size_t)b * 262144;
  auto stage = [&](int kb, int buf) {            // exactly 4 loads/thread
#pragma unroll
    for (int h = 0; h < 2; ++h) {
      int s = h * 256 + tid;                     // A slots 0..511
      int idx = s >> 2, kblk = s & 3;
      int pkc = kblk ^ ((idx >> 2) & 3);
      gl_lds16(xb + (size_t)(row0 + idx) * C_DIM + kb * 32 + pkc * 8,
               &L[buf * 4096 + s * 8]);
    }
#pragma unroll
    for (int h = 0; h < 2; ++h) {
      int s = h * 256 + tid;                     // B slots 0..511
      int kblk = s >> 7, j = s & 127;
      gl_lds16(pbase + ((size_t)(kb * 4 + kblk) * 512 + col0 + j) * 8,
               &L[8192 + buf * 4096 + s * 8]);
    }
  };

  stage(0, 0);
  for (int kb = 0; kb < 16; ++kb) {
    const int cur = kb & 1;
    if (kb < 15) {
      stage(kb + 1, cur ^ 1);                    // next tile flies during MFMA
      VM4;                                       // current tile landed
    } else {
      VMDRAIN;
    }
    __builtin_amdgcn_s_barrier();
    const int krow = lane >> 4;                  // 0..3 (8k each -> K=32)
    const int pk = krow ^ ((lane >> 2) & 3);
    bf16x8 af[4], bfr[4];
#pragma unroll
    for (int t = 0; t < 4; ++t)
      af[t] = *(const bf16x8*)&L[cur * 4096 + ((wr * 64 + t * 16 + (lane & 15)) * 4 + pk) * 8];
#pragma unroll
    for (int t = 0; t < 4; ++t)
      bfr[t] = *(const bf16x8*)&L[8192 + cur * 4096 + (krow * 128 + wc * 64 + t * 16 + (lane & 15)) * 8];
    __builtin_amdgcn_s_setprio(1);
#pragma unroll
    for (int mt = 0; mt < 4; ++mt)
#pragma unroll
      for (int nt = 0; nt < 4; ++nt)
        acc[mt][nt] = __builtin_amdgcn_mfma_f32_16x16x32_bf16(af[mt], bfr[nt], acc[mt][nt], 0, 0, 0);
    __builtin_amdgcn_s_setprio(0);
    __builtin_amdgcn_s_barrier();
  }
  // fp32 epilogue via wave-private 4KB slices
  float* slice = (float*)&L[wid * 4096];
#pragma unroll
  for (int half = 0; half < 2; ++half) {
#pragma unroll
    for (int m2 = 0; m2 < 2; ++m2)
#pragma unroll
      for (int nt = 0; nt < 4; ++nt)
#pragma unroll
        for (int r = 0; r < 4; ++r) {
          int row = m2 * 16 + (lane >> 4) * 4 + r;           // 0..31
          int col = nt * 16 + (lane & 15);
          int slot = (col >> 2) ^ (row & 15);
          slice[row * 64 + slot * 4 + (col & 3)] = acc[half * 2 + m2][nt][r] + bias[nt];
        }
#pragma unroll
    for (int it = 0; it < 8; ++it) {
      int rr = it * 4 + (lane >> 4);                         // 0..31
      int s = (lane & 15) ^ (rr & 15);
      *(float4*)&out[(size_t)(row0 + wr * 64 + half * 32 + rr) * C_DIM + col0 + wc * 64 + (lane & 15) * 4] =
          *(const float4*)&slice[rr * 64 + s * 4];
    }
  }
}

extern "C" void kernel_launch(void* const* d_in, const int* in_sizes, int n_in,
                              void* d_out, int out_size, void* d_ws, size_t ws_size,
                              hipStream_t stream) {
  const float* x      = (const float*)d_in[0];
  const float* qkv_w  = (const float*)d_in[3];
  const float* proj_w = (const float*)d_in[4];
  const float* proj_b = (const float*)d_in[5];
  const float* temp   = (const float*)d_in[6];
  float* out = (float*)d_out;

  char* ws = (char*)d_ws;
  u16* xb  = (u16*)(ws);                              // 67108864
  u16* xbT = (u16*)(ws + 67108864);                   // 67108864
  u16* wl  = (u16*)(ws + 134217728);                  // 1572864
  u16* pwl = (u16*)(ws + 135790592);                  // 524288
  u16* vA  = (u16*)(ws + 136314880);                  // 524288
  u16* Gp  = (u16*)(ws + 136839168);                  // 33554432
  u16* G   = (u16*)(ws + 170393600);                  // 2097152
  u16* Gqk = (u16*)(ws + 172490752);                  // 4194304
  u16* Ml  = (u16*)(ws + 176685056);                  // 2097152
  u16* Pl  = (u16*)(ws + 178782208);                  // 2097152

  k_xcp<<<2368, 512, 0, stream>>>(x, xb, xbT, qkv_w, proj_w, wl, pwl, vA);
  k_g<<<640, 256, 0, stream>>>(xbT, Gp);
  k_red<<<320, 256, 0, stream>>>(Gp, G);
  k_gq<<<1152, 256, 0, stream>>>(G, wl, Gqk, xb);
  k_s2<<<32, 256, 0, stream>>>(Gqk, wl, pwl, temp, Ml);
  k_p<<<64, 256, 0, stream>>>(vA, Ml, Pl);
  k_out<<<2048, 256, 0, stream>>>(xb, Pl, proj_b, out);
}

// Round 19
// 209.727 us; speedup vs baseline: 1.0019x; 1.0019x over previous
//
#include <hip/hip_runtime.h>
#include <stdint.h>
#include <stddef.h>

// FastChannelAttention on MI355X — Gram-refactored pipeline (R18 = revert to
// best-measured R15 configuration, 209.8 us; cooperative fusion abandoned).
//   S[b,h] = Wq_h^T (X_b^T X_b) Wk_h ;  out = X_b (Wv M_b) + bias

typedef unsigned short u16;
typedef __attribute__((ext_vector_type(8))) unsigned short u16x8;
typedef __attribute__((ext_vector_type(8))) __bf16 bf16x8;
typedef __attribute__((ext_vector_type(4))) float f32x4;

#define B_DIM 4
#define N_TOK 16384
#define C_DIM 512
#define CQ3   1536
#define NROWS 65536

__constant__ int PTI[10] = {0, 0, 0, 0, 1, 1, 1, 2, 2, 3};
__constant__ int PTJ[10] = {0, 1, 2, 3, 1, 2, 3, 2, 3, 3};

__device__ __forceinline__ u16 f2bf(float f) {              // RNE fp32->bf16
  union { float f; uint32_t u; } v; v.f = f;
  uint32_t r = v.u + 0x7FFFu + ((v.u >> 16) & 1u);
  return (u16)(r >> 16);
}
__device__ __forceinline__ float bf2f(u16 u) {
  union { uint32_t u; float f; } v; v.u = ((uint32_t)u) << 16;
  return v.f;
}
__device__ __forceinline__ bf16x8 as_bf16x8(u16x8 u) {
  union { u16x8 u; bf16x8 b; } v; v.u = u; return v.b;
}
__device__ __forceinline__ bf16x8 ldfrag(const u16* p) {
  return as_bf16x8(*(const u16x8*)p);
}
__device__ __forceinline__ void gl_lds16(const void* g, void* l) {
  __builtin_amdgcn_global_load_lds(
      (const __attribute__((address_space(1))) uint32_t*)g,
      (__attribute__((address_space(3))) uint32_t*)l, 16, 0, 0);
}
#define VMDRAIN asm volatile("s_waitcnt vmcnt(0)" ::: "memory")
#define VM4     asm volatile("s_waitcnt vmcnt(4)" ::: "memory")
#define VM8     asm volatile("s_waitcnt vmcnt(8)" ::: "memory")

// ---------------- k_xcp: fused x->xb+xbT transpose AND weight prep ----------------
__global__ __launch_bounds__(256) void k_xcp(const float* __restrict__ x,
                                             u16* __restrict__ xb,
                                             u16* __restrict__ xbT,
                                             const float* __restrict__ qkv_w,
                                             const float* __restrict__ proj_w,
                                             u16* __restrict__ wl,
                                             u16* __restrict__ pwl,
                                             u16* __restrict__ vA) {
  __shared__ __align__(16) u16 T[16384];
  const int bi = blockIdx.x;                    // 2688 = 2048 xc + 640 prep
  const int tid = threadIdx.x;
  if (bi >= 2048) {
    int g = (bi - 2048) * 256 + tid;
    if (g < 98304) {                             // wl slots
      int c8 = g / CQ3, j = g - c8 * CQ3;
      u16x8 o;
#pragma unroll
      for (int i = 0; i < 8; ++i) o[i] = f2bf(qkv_w[(size_t)(c8 * 8 + i) * CQ3 + j]);
      *(u16x8*)(wl + (size_t)g * 8) = o;
    } else if (g < 131072) {                     // pwl slots
      int gg = g - 98304;
      int d8 = gg >> 9, j = gg & 511;
      u16x8 o;
#pragma unroll
      for (int i = 0; i < 8; ++i) o[i] = f2bf(proj_w[(size_t)(d8 * 8 + i) * 512 + j]);
      *(u16x8*)(pwl + (size_t)gg * 8) = o;
    } else {                                     // vA row-major chunks
      int gg = g - 131072;
      int c = gg >> 6, q = gg & 63;
      const float* s = qkv_w + (size_t)c * CQ3 + 1024 + q * 8;
      float4 v0 = *(const float4*)s, v1 = *(const float4*)(s + 4);
      u16x8 o;
      o[0] = f2bf(v0.x); o[1] = f2bf(v0.y); o[2] = f2bf(v0.z); o[3] = f2bf(v0.w);
      o[4] = f2bf(v1.x); o[5] = f2bf(v1.y); o[6] = f2bf(v1.z); o[7] = f2bf(v1.w);
      *(u16x8*)(vA + (size_t)gg * 8) = o;
    }
    return;
  }
  const int b = bi >> 9, tt = (bi >> 2) & 127, ct = bi & 3;
  const int n0 = tt * 128, c0 = ct * 128;
  const int cb8 = (tid & 15) * 8;               // channel sub-block
  const int tch = tid >> 4;                     // token chunk 0..15
  const float* src = x + (size_t)(b * N_TOK + n0 + tch * 8) * C_DIM + c0 + cb8;
  float v[8][8];
#pragma unroll
  for (int j = 0; j < 8; ++j) {
    float4 a0 = *(const float4*)(src + (size_t)j * C_DIM);
    float4 a1 = *(const float4*)(src + (size_t)j * C_DIM + 4);
    v[j][0] = a0.x; v[j][1] = a0.y; v[j][2] = a0.z; v[j][3] = a0.w;
    v[j][4] = a1.x; v[j][5] = a1.y; v[j][6] = a1.z; v[j][7] = a1.w;
  }
  u16* xbd = xb + (size_t)(b * N_TOK + n0 + tch * 8) * C_DIM + c0 + cb8;
#pragma unroll
  for (int j = 0; j < 8; ++j) {
    u16x8 o;
#pragma unroll
    for (int i = 0; i < 8; ++i) o[i] = f2bf(v[j][i]);
    *(u16x8*)(xbd + (size_t)j * C_DIM) = o;
  }
#pragma unroll
  for (int i = 0; i < 8; ++i) {
    int c_loc = cb8 + i;
    int pc = tch ^ (tid & 15);
    u16x8 o;
#pragma unroll
    for (int j = 0; j < 8; ++j) o[j] = f2bf(v[j][i]);
    *(u16x8*)&T[c_loc * 128 + pc * 8] = o;
  }
  __syncthreads();
#pragma unroll
  for (int t = 0; t < 8; ++t) {
    int c_loc = t * 16 + (tid >> 4);
    int lch = tid & 15;
    int pc = lch ^ ((c_loc >> 3) & 15);
    u16x8 o = *(const u16x8*)&T[c_loc * 128 + pc * 8];
    *(u16x8*)&xbT[(size_t)(b * C_DIM + c0 + c_loc) * N_TOK + n0 + lch * 8] = o;
  }
}

// ---------------- k_g: Gram partials, triangle pairs, counted vmcnt(8) ----------------
__global__ __launch_bounds__(256) void k_g(const u16* __restrict__ xbT, u16* __restrict__ Gp) {
  __shared__ __align__(16) u16 As[2][8192];   // [buf][idx 128][kblk 8][8], pre-swizzled k
  __shared__ __align__(16) u16 Bs[2][8192];
  const int tid = threadIdx.x, lane = tid & 63, wid = tid >> 6;
  const int orig = blockIdx.x;                  // 640 = 8 x 80 bijective swizzle
  const int wg = (orig & 7) * 80 + (orig >> 3);
  const int kc = wg / 40, rem = wg % 40;
  const int b = rem / 10, p = rem % 10;
  const int ti = PTI[p], tj = PTJ[p];
  const u16* abase = xbT + ((size_t)b * 512 + ti * 128) * N_TOK + kc * 1024;
  const u16* bbase = xbT + ((size_t)b * 512 + tj * 128) * N_TOK + kc * 1024;
  const int wr = wid >> 1, wc = wid & 1;

  auto stage = [&](int kb, int buf) {           // 8 loads/thread
#pragma unroll
    for (int s4 = 0; s4 < 4; ++s4) {
      int slot = s4 * 256 + tid;
      int idx = slot >> 3, kblk = slot & 7;
      int kcol = kb * 64 + ((kblk ^ (idx & 7)) * 8);
      gl_lds16(abase + (size_t)idx * N_TOK + kcol, &As[buf][slot * 8]);
      gl_lds16(bbase + (size_t)idx * N_TOK + kcol, &Bs[buf][slot * 8]);
    }
  };

  f32x4 acc[4][4];
#pragma unroll
  for (int i = 0; i < 4; ++i)
#pragma unroll
    for (int j = 0; j < 4; ++j) acc[i][j] = (f32x4){0.f, 0.f, 0.f, 0.f};

  stage(0, 0);
  for (int kb = 0; kb < 16; ++kb) {
    const int cur = kb & 1;
    if (kb < 15) {
      stage(kb + 1, cur ^ 1);                   // next tile flies through MFMA
      VM8;                                      // current tile landed (newest 8 allowed)
    } else {
      VMDRAIN;
    }
    __builtin_amdgcn_s_barrier();               // current tile collectively visible
#pragma unroll
    for (int kk = 0; kk < 2; ++kk) {
      const int krow = kk * 4 + (lane >> 4);
      const int pk = krow ^ (lane & 7);
      bf16x8 af[4], bfr[4];
#pragma unroll
      for (int t = 0; t < 4; ++t)
        af[t] = *(const bf16x8*)&As[cur][((wr * 64 + t * 16 + (lane & 15)) * 8 + pk) * 8];
#pragma unroll
      for (int t = 0; t < 4; ++t)
        bfr[t] = *(const bf16x8*)&Bs[cur][((wc * 64 + t * 16 + (lane & 15)) * 8 + pk) * 8];
      __builtin_amdgcn_s_setprio(1);
#pragma unroll
      for (int mt = 0; mt < 4; ++mt)
#pragma unroll
        for (int nt = 0; nt < 4; ++nt)
          acc[mt][nt] = __builtin_amdgcn_mfma_f32_16x16x32_bf16(af[mt], bfr[nt], acc[mt][nt], 0, 0, 0);
      __builtin_amdgcn_s_setprio(0);
    }
    __builtin_amdgcn_s_barrier();               // readers done before next overwrite
  }
  // epilogue: 64x64 bf16 per wave via wave-private 8KB slice of As
  u16* wsl = &As[0][0] + wid * 4096;
#pragma unroll
  for (int mt = 0; mt < 4; ++mt)
#pragma unroll
    for (int nt = 0; nt < 4; ++nt)
#pragma unroll
      for (int r = 0; r < 4; ++r) {
        int row = mt * 16 + (lane >> 4) * 4 + r;
        int col = nt * 16 + (lane & 15);
        int slot = (col >> 3) ^ (row & 7);
        wsl[row * 64 + slot * 8 + (col & 7)] = f2bf(acc[mt][nt][r]);
      }
  u16* gdst = Gp + (size_t)(kc * 4 + b) * 262144;
#pragma unroll
  for (int it = 0; it < 8; ++it) {
    int rr = it * 8 + (lane >> 3);
    int slot = (lane & 7) ^ (rr & 7);
    *(u16x8*)&gdst[(size_t)(ti * 128 + wr * 64 + rr) * 512 + tj * 128 + wc * 64 + (lane & 7) * 8] =
        *(const u16x8*)&wsl[rr * 64 + slot * 8];
  }
}

// ---------------- k_red: G(upper) = sum_kc Gp; mirror folded in ----------------
__global__ __launch_bounds__(256) void k_red(const u16* __restrict__ Gp, u16* __restrict__ G) {
  const int bi = blockIdx.x;                    // 320 = b(4) x p(10) x slice(8)
  const int b = bi / 80, rem = bi % 80;
  const int p = rem >> 3, sl = rem & 7;
  const int ti = PTI[p], tj = PTJ[p];
  const int tid = threadIdx.x;
  const int row = sl * 16 + (tid >> 4);         // 0..127 within tile
  const int c0 = (tid & 15) * 8;                // col chunk
  const size_t off = (size_t)(ti * 128 + row) * 512 + tj * 128 + c0;
  float s[8];
#pragma unroll
  for (int i = 0; i < 8; ++i) s[i] = 0.f;
  const u16* src = Gp + (size_t)b * 262144 + off;
#pragma unroll 4
  for (int kc = 0; kc < 16; ++kc) {
    u16x8 v = *(const u16x8*)(src + (size_t)kc * 1048576);
#pragma unroll
    for (int i = 0; i < 8; ++i) s[i] += bf2f(v[i]);
  }
  u16x8 o;
#pragma unroll
  for (int i = 0; i < 8; ++i) o[i] = f2bf(s[i]);
  u16* gb = G + (size_t)b * 262144;
  *(u16x8*)(gb + off) = o;
  if (ti != tj) {                               // mirror: G[c][r] = G[r][c]
#pragma unroll
    for (int i = 0; i < 8; ++i)
      gb[(size_t)(tj * 128 + c0 + i) * 512 + ti * 128 + row] = o[i];
  }
}

// ---------------- k_gq: Gqk = G @ [Wq|Wk]  (blocks >=128: xb L3 prewarm) ----------------
__global__ __launch_bounds__(256) void k_gq(const u16* __restrict__ G,
                                            const u16* __restrict__ wl,
                                            u16* __restrict__ Gqk,
                                            const u16* __restrict__ xb) {
  const int bi = blockIdx.x;                     // 1152 = 128 compute + 1024 prewarm
  if (bi >= 128) {
    const float4* p = (const float4*)xb;         // 67108864 B = 4194304 float4
    float sx = 0.f, sy = 0.f, sz = 0.f, sw = 0.f;
    for (size_t i = (size_t)(bi - 128) * 256 + threadIdx.x; i < 4194304;
         i += (size_t)1024 * 256) {
      float4 v = p[i];
      sx += v.x; sy += v.y; sz += v.z; sw += v.w;
    }
    asm volatile("" :: "v"(sx), "v"(sy), "v"(sz), "v"(sw));
    return;
  }
  const int b = bi >> 5, mt = (bi >> 3) & 3, nt2 = bi & 7;
  const int m0 = mt * 128, n0 = nt2 * 128;
  const int lane = threadIdx.x & 63, w = threadIdx.x >> 6;
  f32x4 acc[8][2];
#pragma unroll
  for (int i = 0; i < 8; ++i) { acc[i][0] = (f32x4){0,0,0,0}; acc[i][1] = (f32x4){0,0,0,0}; }
  for (int ks = 0; ks < 16; ++ks) {
    bf16x8 bfr[2];
#pragma unroll
    for (int nf = 0; nf < 2; ++nf)
      bfr[nf] = ldfrag(wl + ((size_t)(ks * 4 + (lane >> 4)) * CQ3 + n0 + w * 32 + nf * 16 + (lane & 15)) * 8);
#pragma unroll
    for (int mf = 0; mf < 8; ++mf) {
      bf16x8 af = ldfrag(G + (size_t)b * 262144 + (size_t)(m0 + mf * 16 + (lane & 15)) * 512 + ks * 32 + (lane >> 4) * 8);
#pragma unroll
      for (int nf = 0; nf < 2; ++nf)
        acc[mf][nf] = __builtin_amdgcn_mfma_f32_16x16x32_bf16(af, bfr[nf], acc[mf][nf], 0, 0, 0);
    }
  }
#pragma unroll
  for (int mf = 0; mf < 8; ++mf)
#pragma unroll
    for (int nf = 0; nf < 2; ++nf)
#pragma unroll
      for (int r = 0; r < 4; ++r) {
        int d = m0 + mf * 16 + (lane >> 4) * 4 + r;
        int j = n0 + w * 32 + nf * 16 + (lane & 15);
        Gqk[(size_t)b * 524288 + ((size_t)(d >> 3) * 1024 + j) * 8 + (d & 7)] = f2bf(acc[mf][nf][r]);
      }
}

// ---------------- k_s2: per (b,h) S, ssq, softmax, M ----------------
__global__ __launch_bounds__(256) void k_s2(const u16* __restrict__ Gqk,
                                            const u16* __restrict__ wl,
                                            const u16* __restrict__ pwl,
                                            const float* __restrict__ temp,
                                            u16* __restrict__ Ml) {
  __shared__ float Ssh[4][4096];
  __shared__ u16 At[64 * 72];
  __shared__ float ssqsh[128];
  __shared__ float rqk[128];
  const int tid = threadIdx.x, lane = tid & 63, w = tid >> 6;
  const int bh = blockIdx.x, b = bh >> 3, hh = bh & 7;
  if (tid < 128) ssqsh[tid] = 0.f;

  f32x4 acc[4][4];
#pragma unroll
  for (int i = 0; i < 4; ++i)
#pragma unroll
    for (int j = 0; j < 4; ++j) acc[i][j] = (f32x4){0.f, 0.f, 0.f, 0.f};
  for (int ks = 0; ks < 4; ++ks) {
    const int crow = w * 16 + ks * 4 + (lane >> 4);
    bf16x8 aq[4], bk[4];
#pragma unroll
    for (int mf = 0; mf < 4; ++mf)
      aq[mf] = ldfrag(wl + ((size_t)crow * CQ3 + hh * 64 + mf * 16 + (lane & 15)) * 8);
#pragma unroll
    for (int nf = 0; nf < 4; ++nf)
      bk[nf] = ldfrag(Gqk + (size_t)b * 524288 + ((size_t)crow * 1024 + 512 + hh * 64 + nf * 16 + (lane & 15)) * 8);
#pragma unroll
    for (int mf = 0; mf < 4; ++mf)
#pragma unroll
      for (int nf = 0; nf < 4; ++nf)
        acc[mf][nf] = __builtin_amdgcn_mfma_f32_16x16x32_bf16(aq[mf], bk[nf], acc[mf][nf], 0, 0, 0);
  }
#pragma unroll
  for (int mf = 0; mf < 4; ++mf)
#pragma unroll
    for (int nf = 0; nf < 4; ++nf)
#pragma unroll
      for (int r = 0; r < 4; ++r)
        Ssh[w][(mf * 16 + (lane >> 4) * 4 + r) * 64 + nf * 16 + (lane & 15)] = acc[mf][nf][r];
  __syncthreads();
  for (int idx = tid; idx < 4096; idx += 256)
    Ssh[0][idx] = Ssh[0][idx] + Ssh[1][idx] + Ssh[2][idx] + Ssh[3][idx];

  {
    const int d = tid & 63, part = tid >> 6;
    float sq = 0.f, sk = 0.f;
    for (int co = 0; co < 16; ++co) {
      int c8 = part * 16 + co;
      u16x8 wq = *(const u16x8*)(wl + ((size_t)c8 * CQ3 + hh * 64 + d) * 8);
      u16x8 gq = *(const u16x8*)(Gqk + (size_t)b * 524288 + ((size_t)c8 * 1024 + hh * 64 + d) * 8);
      u16x8 wk = *(const u16x8*)(wl + ((size_t)c8 * CQ3 + 512 + hh * 64 + d) * 8);
      u16x8 gk = *(const u16x8*)(Gqk + (size_t)b * 524288 + ((size_t)c8 * 1024 + 512 + hh * 64 + d) * 8);
#pragma unroll
      for (int i = 0; i < 8; ++i) {
        sq += bf2f(wq[i]) * bf2f(gq[i]);
        sk += bf2f(wk[i]) * bf2f(gk[i]);
      }
    }
    atomicAdd(&ssqsh[d], sq);
    atomicAdd(&ssqsh[64 + d], sk);
  }
  __syncthreads();
  if (tid < 128) rqk[tid] = 1.f / fmaxf(sqrtf(fmaxf(ssqsh[tid], 0.f)), 1e-12f);
  __syncthreads();

  {
    const float tp = temp[hh];
    const int d = tid >> 2, q4 = tid & 3;
    float vals[16];
    float mx = -3.0e38f;
    const float rqd = rqk[d];
#pragma unroll
    for (int i = 0; i < 16; ++i) {
      float v = Ssh[0][d * 64 + q4 * 16 + i] * rqd * rqk[64 + q4 * 16 + i] * tp;
      vals[i] = v; mx = fmaxf(mx, v);
    }
    mx = fmaxf(mx, __shfl_xor(mx, 1));
    mx = fmaxf(mx, __shfl_xor(mx, 2));
    float sum = 0.f;
#pragma unroll
    for (int i = 0; i < 16; ++i) { vals[i] = __expf(vals[i] - mx); sum += vals[i]; }
    sum += __shfl_xor(sum, 1);
    sum += __shfl_xor(sum, 2);
    const float inv = 1.f / sum;
#pragma unroll
    for (int i = 0; i < 16; ++i) At[(q4 * 16 + i) * 72 + d] = f2bf(vals[i] * inv);
  }
  __syncthreads();

  f32x4 acc2[4][8];
#pragma unroll
  for (int i = 0; i < 4; ++i)
#pragma unroll
    for (int j = 0; j < 8; ++j) acc2[i][j] = (f32x4){0.f, 0.f, 0.f, 0.f};
#pragma unroll
  for (int s = 0; s < 2; ++s) {
    bf16x8 af[4], bfr[8];
#pragma unroll
    for (int mf = 0; mf < 4; ++mf)
      af[mf] = *(const bf16x8*)&At[(mf * 16 + (lane & 15)) * 72 + s * 32 + (lane >> 4) * 8];
#pragma unroll
    for (int nf = 0; nf < 8; ++nf)
      bfr[nf] = ldfrag(pwl + ((size_t)(hh * 8 + s * 4 + (lane >> 4)) * 512 + w * 128 + nf * 16 + (lane & 15)) * 8);
#pragma unroll
    for (int mf = 0; mf < 4; ++mf)
#pragma unroll
      for (int nf = 0; nf < 8; ++nf)
        acc2[mf][nf] = __builtin_amdgcn_mfma_f32_16x16x32_bf16(af[mf], bfr[nf], acc2[mf][nf], 0, 0, 0);
  }
#pragma unroll
  for (int mf = 0; mf < 4; ++mf)
#pragma unroll
    for (int nf = 0; nf < 8; ++nf)
#pragma unroll
      for (int r = 0; r < 4; ++r) {
        int e = mf * 16 + (lane >> 4) * 4 + r;
        int j = w * 128 + nf * 16 + (lane & 15);
        int cc = hh * 64 + e;
        Ml[(size_t)b * 262144 + ((size_t)(cc >> 3) * 512 + j) * 8 + (cc & 7)] = f2bf(acc2[mf][nf][r]);
      }
}

// ---------------- k_p: Pl = Wv @ Ml ----------------
__global__ __launch_bounds__(256) void k_p(const u16* __restrict__ vA,
                                           const u16* __restrict__ Ml,
                                           u16* __restrict__ Pl) {
  const int bi = blockIdx.x;                     // 64: b(4) x ct(4) x jt(4)
  const int b = bi >> 4, ct = (bi >> 2) & 3, jt = bi & 3;
  const int m0 = ct * 128, j0 = jt * 128;
  const int lane = threadIdx.x & 63, w = threadIdx.x >> 6;
  f32x4 acc[8][2];
#pragma unroll
  for (int i = 0; i < 8; ++i) { acc[i][0] = (f32x4){0,0,0,0}; acc[i][1] = (f32x4){0,0,0,0}; }
  for (int ks = 0; ks < 16; ++ks) {
    bf16x8 bfr[2];
#pragma unroll
    for (int nf = 0; nf < 2; ++nf)
      bfr[nf] = ldfrag(Ml + (size_t)b * 262144 + ((size_t)(ks * 4 + (lane >> 4)) * 512 + j0 + w * 32 + nf * 16 + (lane & 15)) * 8);
#pragma unroll
    for (int mf = 0; mf < 8; ++mf) {
      bf16x8 af = ldfrag(vA + (size_t)(m0 + mf * 16 + (lane & 15)) * 512 + ks * 32 + (lane >> 4) * 8);
#pragma unroll
      for (int nf = 0; nf < 2; ++nf)
        acc[mf][nf] = __builtin_amdgcn_mfma_f32_16x16x32_bf16(af, bfr[nf], acc[mf][nf], 0, 0, 0);
    }
  }
#pragma unroll
  for (int mf = 0; mf < 8; ++mf)
#pragma unroll
    for (int nf = 0; nf < 2; ++nf)
#pragma unroll
      for (int r = 0; r < 4; ++r) {
        int c = m0 + mf * 16 + (lane >> 4) * 4 + r;
        int j = j0 + w * 32 + nf * 16 + (lane & 15);
        Pl[(size_t)b * 262144 + ((size_t)(c >> 3) * 512 + j) * 8 + (c & 7)] = f2bf(acc[mf][nf][r]);
      }
}

// ---------------- k_out: out = xb @ Pl + bias; BK=32 dbuf, counted vmcnt(4) ----------------
__global__ __launch_bounds__(256, 4) void k_out(const u16* __restrict__ xb,
                                                const u16* __restrict__ Pl,
                                                const float* __restrict__ pb,
                                                float* __restrict__ out) {
  __shared__ __align__(16) u16 L[16384];
  const int tid = threadIdx.x;
  const int orig = blockIdx.x;                   // 2048 = 8 x 256 bijective swizzle
  const int wg = (orig & 7) * 256 + (orig >> 3);
  const int cb = wg & 3, rb = wg >> 2;
  const int row0 = rb * 128, col0 = cb * 128;
  const int b = rb >> 7;
  const int lane = tid & 63, wid = tid >> 6;
  const int wr = wid >> 1, wc = wid & 1;
  float bias[4];
#pragma unroll
  for (int nt = 0; nt < 4; ++nt) bias[nt] = pb[col0 + wc * 64 + nt * 16 + (lane & 15)];

  f32x4 acc[4][4];
#pragma unroll
  for (int i = 0; i < 4; ++i)
#pragma unroll
    for (int j = 0; j < 4; ++j) acc[i][j] = (f32x4){0.f, 0.f, 0.f, 0.f};

  const u16* pbase = Pl + (size_t)b * 262144;
  auto stage = [&](int kb, int buf) {            // exactly 4 loads/thread
#pragma unroll
    for (int h = 0; h < 2; ++h) {
      int s = h * 256 + tid;                     // A slots 0..511
      int idx = s >> 2, kblk = s & 3;
      int pkc = kblk ^ ((idx >> 2) & 3);
      gl_lds16(xb + (size_t)(row0 + idx) * C_DIM + kb * 32 + pkc * 8,
               &L[buf * 4096 + s * 8]);
    }
#pragma unroll
    for (int h = 0; h < 2; ++h) {
      int s = h * 256 + tid;                     // B slots 0..511
      int kblk = s >> 7, j = s & 127;
      gl_lds16(pbase + ((size_t)(kb * 4 + kblk) * 512 + col0 + j) * 8,
               &L[8192 + buf * 4096 + s * 8]);
    }
  };

  stage(0, 0);
  for (int kb = 0; kb < 16; ++kb) {
    const int cur = kb & 1;
    if (kb < 15) {
      stage(kb + 1, cur ^ 1);                    // next tile flies during MFMA
      VM4;                                       // current tile landed
    } else {
      VMDRAIN;
    }
    __builtin_amdgcn_s_barrier();
    const int krow = lane >> 4;                  // 0..3 (8k each -> K=32)
    const int pk = krow ^ ((lane >> 2) & 3);
    bf16x8 af[4], bfr[4];
#pragma unroll
    for (int t = 0; t < 4; ++t)
      af[t] = *(const bf16x8*)&L[cur * 4096 + ((wr * 64 + t * 16 + (lane & 15)) * 4 + pk) * 8];
#pragma unroll
    for (int t = 0; t < 4; ++t)
      bfr[t] = *(const bf16x8*)&L[8192 + cur * 4096 + (krow * 128 + wc * 64 + t * 16 + (lane & 15)) * 8];
    __builtin_amdgcn_s_setprio(1);
#pragma unroll
    for (int mt = 0; mt < 4; ++mt)
#pragma unroll
      for (int nt = 0; nt < 4; ++nt)
        acc[mt][nt] = __builtin_amdgcn_mfma_f32_16x16x32_bf16(af[mt], bfr[nt], acc[mt][nt], 0, 0, 0);
    __builtin_amdgcn_s_setprio(0);
    __builtin_amdgcn_s_barrier();
  }
  // fp32 epilogue via wave-private 4KB slices
  float* slice = (float*)&L[wid * 4096];
#pragma unroll
  for (int half = 0; half < 2; ++half) {
#pragma unroll
    for (int m2 = 0; m2 < 2; ++m2)
#pragma unroll
      for (int nt = 0; nt < 4; ++nt)
#pragma unroll
        for (int r = 0; r < 4; ++r) {
          int row = m2 * 16 + (lane >> 4) * 4 + r;           // 0..31
          int col = nt * 16 + (lane & 15);
          int slot = (col >> 2) ^ (row & 15);
          slice[row * 64 + slot * 4 + (col & 3)] = acc[half * 2 + m2][nt][r] + bias[nt];
        }
#pragma unroll
    for (int it = 0; it < 8; ++it) {
      int rr = it * 4 + (lane >> 4);                         // 0..31
      int s = (lane & 15) ^ (rr & 15);
      *(float4*)&out[(size_t)(row0 + wr * 64 + half * 32 + rr) * C_DIM + col0 + wc * 64 + (lane & 15) * 4] =
          *(const float4*)&slice[rr * 64 + s * 4];
    }
  }
}

extern "C" void kernel_launch(void* const* d_in, const int* in_sizes, int n_in,
                              void* d_out, int out_size, void* d_ws, size_t ws_size,
                              hipStream_t stream) {
  const float* x      = (const float*)d_in[0];
  const float* qkv_w  = (const float*)d_in[3];
  const float* proj_w = (const float*)d_in[4];
  const float* proj_b = (const float*)d_in[5];
  const float* temp   = (const float*)d_in[6];
  float* out = (float*)d_out;

  char* ws = (char*)d_ws;
  u16* xb  = (u16*)(ws);                              // 67108864
  u16* xbT = (u16*)(ws + 67108864);                   // 67108864
  u16* wl  = (u16*)(ws + 134217728);                  // 1572864
  u16* pwl = (u16*)(ws + 135790592);                  // 524288
  u16* vA  = (u16*)(ws + 136314880);                  // 524288
  u16* Gp  = (u16*)(ws + 136839168);                  // 33554432
  u16* G   = (u16*)(ws + 170393600);                  // 2097152
  u16* Gqk = (u16*)(ws + 172490752);                  // 4194304
  u16* Ml  = (u16*)(ws + 176685056);                  // 2097152
  u16* Pl  = (u16*)(ws + 178782208);                  // 2097152

  k_xcp<<<2688, 256, 0, stream>>>(x, xb, xbT, qkv_w, proj_w, wl, pwl, vA);
  k_g<<<640, 256, 0, stream>>>(xbT, Gp);
  k_red<<<320, 256, 0, stream>>>(Gp, G);
  k_gq<<<1152, 256, 0, stream>>>(G, wl, Gqk, xb);
  k_s2<<<32, 256, 0, stream>>>(Gqk, wl, pwl, temp, Ml);
  k_p<<<64, 256, 0, stream>>>(vA, Ml, Pl);
  k_out<<<2048, 256, 0, stream>>>(xb, Pl, proj_b, out);
}